// Round 1
// baseline (725.528 us; speedup 1.0000x reference)
//
#include <hip/hip_runtime.h>
#include <hip/hip_bf16.h>
#include <math.h>
#include <stdint.h>

#define DEVI static __device__ __forceinline__

typedef __attribute__((ext_vector_type(8))) short short8;       // MFMA A/B frag (8 bf16)
typedef __attribute__((ext_vector_type(4))) float f32x4;        // MFMA C/D frag
typedef __attribute__((ext_vector_type(4))) float float4v;
typedef __attribute__((ext_vector_type(4))) unsigned short ushort4v;
typedef __attribute__((ext_vector_type(8))) unsigned short ushort8;

// fp32 -> bf16 bits, round-to-nearest-even (finite inputs only)
DEVI unsigned short f2bf(float f) {
  unsigned int u = __builtin_bit_cast(unsigned int, f);
  u += 0x7fffu + ((u >> 16) & 1u);
  return (unsigned short)(u >> 16);
}
DEVI float bf2f(unsigned short s) {
  unsigned int u = ((unsigned int)s) << 16;
  return __builtin_bit_cast(float, u);
}

// async global->LDS, 16B per lane. lds ptr must be wave-uniform base; HW adds lane*16.
DEVI void gl_lds16(const unsigned short* g, unsigned short* l) {
  __builtin_amdgcn_global_load_lds(
      (const __attribute__((address_space(1))) void*)g,
      (__attribute__((address_space(3))) void*)l, 16, 0, 0);
}

// dst[r][c] = (r<srcR && c<srcC) ? bf16(src[r][c]) : 0   (dstC % 4 == 0)
__global__ __launch_bounds__(256) void cast_pad(const float* __restrict__ src,
                                                unsigned short* __restrict__ dst,
                                                int srcR, int srcC, int dstR, int dstC) {
  size_t n4 = (size_t)dstR * (size_t)dstC / 4;
  for (size_t i = (size_t)blockIdx.x * blockDim.x + threadIdx.x; i < n4;
       i += (size_t)gridDim.x * blockDim.x) {
    size_t e = i * 4;
    int r = (int)(e / (size_t)dstC);
    int c = (int)(e % (size_t)dstC);
    float4v v;
    if (r < srcR && c + 3 < srcC) {
      v = *(const float4v*)(src + (size_t)r * srcC + c);
    } else {
#pragma unroll
      for (int j = 0; j < 4; ++j) {
        int cc = c + j;
        v[j] = (r < srcR && cc < srcC) ? src[(size_t)r * srcC + cc] : 0.f;
      }
    }
    ushort4v o;
#pragma unroll
    for (int j = 0; j < 4; ++j) o[j] = f2bf(v[j]);
    *(ushort4v*)(dst + e) = o;
  }
}

// C = A @ Bt^T (+ epilogue). A [M x K] bf16 row-major, Bt [N x K] bf16 row-major.
// Tile 128x128, BK=64, 256 threads = 4 waves (2x2), wave tile 64x64 = 4x4 frags of 16x16x32.
// EPI 0: +bias -> bf16.  EPI 1: +bias, ReLU, BN(g,be,m,v) -> bf16.
template <int EPI>
__global__ __launch_bounds__(256) void gemm_bt(
    const unsigned short* __restrict__ A, const unsigned short* __restrict__ Bt,
    unsigned short* __restrict__ C, int M, int N, int K,
    const float* __restrict__ bias, int biasN,
    const float* __restrict__ g, const float* __restrict__ be,
    const float* __restrict__ mn, const float* __restrict__ vr) {
  __shared__ unsigned short lA[128 * 64];
  __shared__ unsigned short lB[128 * 64];
  const int tid = threadIdx.x;
  const int wid = tid >> 6;
  const int lane = tid & 63;
  const int rowA0 = blockIdx.x * 128;
  const int rowB0 = blockIdx.y * 128;
  const int wr = (wid >> 1) * 64;   // wave row offset in tile
  const int wc = (wid & 1) * 64;    // wave col offset in tile
  const int frow = lane & 15;       // A/B frag row within 16
  const int fk8 = (lane >> 4) * 8;  // k offset within 32

  f32x4 acc[4][4] = {};

  for (int k0 = 0; k0 < K; k0 += 64) {
    __syncthreads();  // previous compute done before overwriting LDS
#pragma unroll
    for (int i = 0; i < 4; ++i) {
      int basechunk = i * 256 + wid * 64;  // wave-uniform
      int chunk = basechunk + lane;
      int r = chunk >> 3;      // 8 chunks (of 8 bf16) per 64-col row
      int cc = chunk & 7;
      gl_lds16(A + (size_t)(rowA0 + r) * K + (k0 + cc * 8), lA + basechunk * 8);
      gl_lds16(Bt + (size_t)(rowB0 + r) * K + (k0 + cc * 8), lB + basechunk * 8);
    }
    __syncthreads();  // compiler drains vmcnt before barrier -> LDS ready
#pragma unroll
    for (int kk = 0; kk < 2; ++kk) {
      short8 af[4], bfr[4];
#pragma unroll
      for (int fm = 0; fm < 4; ++fm)
        af[fm] = *(const short8*)(lA + (wr + fm * 16 + frow) * 64 + kk * 32 + fk8);
#pragma unroll
      for (int fn = 0; fn < 4; ++fn)
        bfr[fn] = *(const short8*)(lB + (wc + fn * 16 + frow) * 64 + kk * 32 + fk8);
#pragma unroll
      for (int fm = 0; fm < 4; ++fm)
#pragma unroll
        for (int fn = 0; fn < 4; ++fn)
          acc[fm][fn] =
              __builtin_amdgcn_mfma_f32_16x16x32_bf16(af[fm], bfr[fn], acc[fm][fn], 0, 0, 0);
    }
  }

  // epilogue: C/D layout col = lane&15, row = (lane>>4)*4 + r
  const int rl = (lane >> 4) * 4;
#pragma unroll
  for (int fn = 0; fn < 4; ++fn) {
    int gc = rowB0 + wc + fn * 16 + frow;
    float bb = (gc < biasN) ? bias[gc] : 0.f;
    float gg = 1.f, bbe = 0.f, mm = 0.f, rs = 1.f;
    if (EPI == 1) {
      gg = g[gc];
      bbe = be[gc];
      mm = mn[gc];
      rs = rsqrtf(vr[gc] + 1e-5f);
    }
#pragma unroll
    for (int fm = 0; fm < 4; ++fm) {
      f32x4 v = acc[fm][fn];
#pragma unroll
      for (int r = 0; r < 4; ++r) {
        int gr = rowA0 + wr + fm * 16 + rl + r;
        float x = v[r] + bb;
        if (EPI == 1) {
          x = fmaxf(x, 0.f);
          x = gg * (x - mm) * rs + bbe;
        }
        C[(size_t)gr * N + gc] = f2bf(x);
      }
    }
  }
}

// Per-row windowed average within consecutive-equal-key segments.
// 1 block (256 thr) per row, 8 features/thread (D must be 8*blockDim).
__global__ __launch_bounds__(256) void pool_seg(const unsigned short* __restrict__ h,
                                                const int* __restrict__ key,
                                                unsigned short* __restrict__ pooled,
                                                int B, int D) {
  int row = blockIdx.x;
  int k0 = key[row];
  int down = 0, up = 0;
  while (down < 4 && row - down - 1 >= 0 && key[row - down - 1] == k0) ++down;
  while (up < 4 && row + up + 1 < B && key[row + up + 1] == k0) ++up;
  float inv = 1.f / (float)(down + up + 1);
  int f0 = threadIdx.x * 8;
  float s[8] = {0.f, 0.f, 0.f, 0.f, 0.f, 0.f, 0.f, 0.f};
  for (int dr = -down; dr <= up; ++dr) {
    ushort8 v = *(const ushort8*)(h + (size_t)(row + dr) * D + f0);
#pragma unroll
    for (int j = 0; j < 8; ++j) s[j] += bf2f(v[j]);
  }
  ushort8 o;
#pragma unroll
  for (int j = 0; j < 8; ++j) o[j] = f2bf(s[j] * inv);
  *(ushort8*)(pooled + (size_t)row * D + f0) = o;
}

// out rows: output_pain [B,2] then pain_pred [B,2]. 1 block per row, H = 8*blockDim.
__global__ __launch_bounds__(256) void final_head(const unsigned short* __restrict__ h2,
                                                  const float* __restrict__ Wp,
                                                  const float* __restrict__ bp,
                                                  float* __restrict__ out, int B, int H) {
  int row = blockIdx.x;
  int f0 = threadIdx.x * 8;
  ushort8 v = *(const ushort8*)(h2 + (size_t)row * H + f0);
  float4v w0a = *(const float4v*)(Wp + f0);
  float4v w0b = *(const float4v*)(Wp + f0 + 4);
  float4v w1a = *(const float4v*)(Wp + H + f0);
  float4v w1b = *(const float4v*)(Wp + H + f0 + 4);
  float a0 = 0.f, a1 = 0.f;
#pragma unroll
  for (int j = 0; j < 4; ++j) {
    float x0 = bf2f(v[j]), x1 = bf2f(v[j + 4]);
    a0 += x0 * w0a[j] + x1 * w0b[j];
    a1 += x0 * w1a[j] + x1 * w1b[j];
  }
#pragma unroll
  for (int off = 32; off > 0; off >>= 1) {
    a0 += __shfl_down(a0, off);
    a1 += __shfl_down(a1, off);
  }
  __shared__ float red[8];
  int wv = threadIdx.x >> 6;
  if ((threadIdx.x & 63) == 0) {
    red[wv] = a0;
    red[4 + wv] = a1;
  }
  __syncthreads();
  if (threadIdx.x == 0) {
    float o0 = red[0] + red[1] + red[2] + red[3] + bp[0];
    float o1 = red[4] + red[5] + red[6] + red[7] + bp[1];
    out[(size_t)row * 2] = o0;
    out[(size_t)row * 2 + 1] = o1;
    float mx = fmaxf(o0, o1);
    float e0 = expf(o0 - mx), e1 = expf(o1 - mx);
    float sden = e0 + e1;
    out[(size_t)B * 2 + (size_t)row * 2] = e0 / sden;
    out[(size_t)B * 2 + (size_t)row * 2 + 1] = e1 / sden;
  }
}

extern "C" void kernel_launch(void* const* d_in, const int* in_sizes, int n_in,
                              void* d_out, int out_size, void* d_ws, size_t ws_size,
                              hipStream_t stream) {
  (void)n_in; (void)out_size; (void)ws_size;
  const float* img = (const float*)d_in[0];
  const int* segkey = (const int*)d_in[1];
  const float* W3d = (const float*)d_in[2];
  const float* b3d = (const float*)d_in[3];
  const float* W1 = (const float*)d_in[4];
  const float* b1 = (const float*)d_in[5];
  const float* g1 = (const float*)d_in[6];
  const float* be1 = (const float*)d_in[7];
  const float* m1 = (const float*)d_in[8];
  const float* v1 = (const float*)d_in[9];
  const float* W2 = (const float*)d_in[10];
  const float* b2 = (const float*)d_in[11];
  const float* g2 = (const float*)d_in[12];
  const float* be2 = (const float*)d_in[13];
  const float* m2 = (const float*)d_in[14];
  const float* v2 = (const float*)d_in[15];
  const float* Wp = (const float*)d_in[16];
  const float* bp = (const float*)d_in[17];

  const int B = in_sizes[1];           // 16384
  const int F = in_sizes[0] / B;       // 2048
  const int D3 = in_sizes[3];          // 600
  const int H = in_sizes[5];           // 2048
  const int D3p = ((D3 + 127) / 128) * 128;  // 640

  char* ws = (char*)d_ws;
  size_t off = 0;
  auto alloc = [&](size_t bytes) -> void* {
    void* p = (void*)(ws + off);
    off += (bytes + 255) & ~(size_t)255;
    return p;
  };
  unsigned short* imgb = (unsigned short*)alloc((size_t)B * F * 2);     // 67 MB
  unsigned short* W3dp = (unsigned short*)alloc((size_t)D3p * F * 2);   // 2.6 MB
  unsigned short* W1p  = (unsigned short*)alloc((size_t)H * D3p * 2);   // 2.6 MB
  unsigned short* W2b  = (unsigned short*)alloc((size_t)H * H * 2);     // 8.4 MB
  unsigned short* lat  = (unsigned short*)alloc((size_t)B * D3p * 2);   // 21 MB
  unsigned short* h    = (unsigned short*)alloc((size_t)B * H * 2);     // 67 MB
  unsigned short* pooled = (unsigned short*)alloc((size_t)B * H * 2);   // 67 MB
  unsigned short* h2 = imgb;  // img dead after G1 -> reuse for h2

  float* out = (float*)d_out;

  auto gridFor = [](size_t n4) -> int {
    size_t gsz = (n4 + 255) / 256;
    if (gsz > 4096) gsz = 4096;
    return (int)gsz;
  };

  // casts (with zero-padding where needed)
  cast_pad<<<gridFor((size_t)B * F / 4), 256, 0, stream>>>(img, imgb, B, F, B, F);
  cast_pad<<<gridFor((size_t)D3p * F / 4), 256, 0, stream>>>(W3d, W3dp, D3, F, D3p, F);
  cast_pad<<<gridFor((size_t)H * D3p / 4), 256, 0, stream>>>(W1, W1p, H, D3, H, D3p);
  cast_pad<<<gridFor((size_t)H * H / 4), 256, 0, stream>>>(W2, W2b, H, H, H, H);

  dim3 blk(256);
  // G1: latent[B x D3p] = img @ W3d^T + b3d (pad cols produce exact 0)
  gemm_bt<0><<<dim3(B / 128, D3p / 128), blk, 0, stream>>>(
      imgb, W3dp, lat, B, D3p, F, b3d, D3, nullptr, nullptr, nullptr, nullptr);
  // G2: h = BN(ReLU(latent @ W1^T + b1))
  gemm_bt<1><<<dim3(B / 128, H / 128), blk, 0, stream>>>(
      lat, W1p, h, B, H, D3p, b1, H, g1, be1, m1, v1);
  // segment windowed avg pool
  pool_seg<<<B, H / 8, 0, stream>>>(h, segkey, pooled, B, H);
  // G3: h2 = BN(ReLU(pooled @ W2^T + b2))
  gemm_bt<1><<<dim3(B / 128, H / 128), blk, 0, stream>>>(
      pooled, W2b, h2, B, H, H, b2, H, g2, be2, m2, v2);
  // final linear + softmax
  final_head<<<B, H / 8, 0, stream>>>(h2, Wp, bp, out, B, H);
}

// Round 2
// 642.298 us; speedup vs baseline: 1.1296x; 1.1296x over previous
//
#include <hip/hip_runtime.h>
#include <hip/hip_bf16.h>
#include <math.h>
#include <stdint.h>

#define DEVI static __device__ __forceinline__

typedef __attribute__((ext_vector_type(8))) short short8;       // MFMA A/B frag (8 bf16)
typedef __attribute__((ext_vector_type(4))) float f32x4;        // MFMA C/D frag
typedef __attribute__((ext_vector_type(4))) float float4v;
typedef __attribute__((ext_vector_type(4))) unsigned short ushort4v;
typedef __attribute__((ext_vector_type(8))) unsigned short ushort8;

// fp32 -> bf16 bits, round-to-nearest-even (finite inputs only)
DEVI unsigned short f2bf(float f) {
  unsigned int u = __builtin_bit_cast(unsigned int, f);
  u += 0x7fffu + ((u >> 16) & 1u);
  return (unsigned short)(u >> 16);
}
DEVI float bf2f(unsigned short s) {
  unsigned int u = ((unsigned int)s) << 16;
  return __builtin_bit_cast(float, u);
}

// async global->LDS, 16B per lane. lds ptr must be wave-uniform base; HW adds lane*16.
DEVI void gl_lds16(const unsigned short* g, unsigned short* l) {
  __builtin_amdgcn_global_load_lds(
      (const __attribute__((address_space(1))) void*)g,
      (__attribute__((address_space(3))) void*)l, 16, 0, 0);
}

// dst[r][c] = (r<srcR && c<srcC) ? bf16(src[r][c]) : 0   (dstC % 4 == 0)
__global__ __launch_bounds__(256) void cast_pad(const float* __restrict__ src,
                                                unsigned short* __restrict__ dst,
                                                int srcR, int srcC, int dstR, int dstC) {
  size_t n4 = (size_t)dstR * (size_t)dstC / 4;
  for (size_t i = (size_t)blockIdx.x * blockDim.x + threadIdx.x; i < n4;
       i += (size_t)gridDim.x * blockDim.x) {
    size_t e = i * 4;
    int r = (int)(e / (size_t)dstC);
    int c = (int)(e % (size_t)dstC);
    float4v v;
    if (r < srcR && c + 3 < srcC) {
      v = *(const float4v*)(src + (size_t)r * srcC + c);
    } else {
#pragma unroll
      for (int j = 0; j < 4; ++j) {
        int cc = c + j;
        v[j] = (r < srcR && cc < srcC) ? src[(size_t)r * srcC + cc] : 0.f;
      }
    }
    ushort4v o;
#pragma unroll
    for (int j = 0; j < 4; ++j) o[j] = f2bf(v[j]);
    *(ushort4v*)(dst + e) = o;
  }
}

#define BARRIER()                                   \
  do {                                              \
    asm volatile("" ::: "memory");                  \
    __builtin_amdgcn_s_barrier();                   \
    asm volatile("" ::: "memory");                  \
  } while (0)
#define LGKM0_SCHED()                                        \
  do {                                                       \
    asm volatile("s_waitcnt lgkmcnt(0)" ::: "memory");       \
    __builtin_amdgcn_sched_barrier(0);                       \
  } while (0)

// ds_read of A quadrant: fm in [fmBase, fmBase+4), kk 0..1. Swizzled addresses.
#define DSA(fmBase)                                                           \
  _Pragma("unroll") for (int i_ = 0; i_ < 4; ++i_)                            \
  _Pragma("unroll") for (int kk_ = 0; kk_ < 2; ++kk_)                         \
      afr[i_][kk_] = *(const short8*)(ldsc + curOff +                         \
          ((arow0 + ((fmBase) + i_) * 2048 + kk_ * 64 + fk16) ^ xorv));

#define DSB(fnBase)                                                           \
  _Pragma("unroll") for (int j_ = 0; j_ < 2; ++j_)                            \
  _Pragma("unroll") for (int kk_ = 0; kk_ < 2; ++kk_)                         \
      bfr[j_][kk_] = *(const short8*)(ldsc + 65536 + curOff +                 \
          ((brow0 + ((fnBase) + j_) * 2048 + kk_ * 64 + fk16) ^ xorv));

// one C-quadrant: 16 MFMA wrapped in setprio (T5)
#define MFMAQ(fmB, fnB)                                                       \
  __builtin_amdgcn_s_setprio(1);                                              \
  _Pragma("unroll") for (int i_ = 0; i_ < 4; ++i_)                            \
  _Pragma("unroll") for (int j_ = 0; j_ < 2; ++j_)                            \
  _Pragma("unroll") for (int kk_ = 0; kk_ < 2; ++kk_)                         \
      acc[(fmB) + i_][(fnB) + j_] = __builtin_amdgcn_mfma_f32_16x16x32_bf16(  \
          afr[i_][kk_], bfr[j_][kk_], acc[(fmB) + i_][(fnB) + j_], 0, 0, 0);  \
  __builtin_amdgcn_s_setprio(0);                                              \
  __builtin_amdgcn_sched_barrier(0);

// C = A @ Bt^T (+ epilogue). 256x256 tile, BK=64, 512 threads = 8 waves (2M x 4N).
// 8-phase schedule (T3+T4), LDS XOR-swizzle (T2), setprio (T5). 128 KiB dynamic LDS:
// A bufs at bytes [0,65536), B at [65536,131072); each buf 32768 B (256 rows x 64 cols bf16).
// EPI 0: +bias -> bf16.  EPI 1: +bias, ReLU, BN -> bf16.
template <int EPI>
__global__ __launch_bounds__(512, 1) void gemm8p(
    const unsigned short* __restrict__ A, const unsigned short* __restrict__ Bt,
    unsigned short* __restrict__ C, int M, int N, int K,
    const float* __restrict__ bias, int biasN,
    const float* __restrict__ g, const float* __restrict__ be,
    const float* __restrict__ mn, const float* __restrict__ vr) {
  extern __shared__ unsigned short lds[];
  char* ldsc = (char*)lds;
  const int tid = threadIdx.x;
  const int wid = tid >> 6;
  const int lane = tid & 63;
  const int wave_m = wid >> 2;   // 0..1
  const int wave_n = wid & 3;    // 0..3
  const int rowA0 = blockIdx.x * 256;
  const int rowB0 = blockIdx.y * 256;
  const int frow = lane & 15;
  const int fk16 = (lane >> 4) * 16;        // byte offset of k-subfrag within 64B row-k span
  const int xorv = (frow & 7) << 4;         // T2 swizzle term (row&7)<<4
  const int arow0 = (wave_m * 128 + frow) * 128;  // tile-byte row base (fm=0)
  const int brow0 = (wave_n * 64 + frow) * 128;
  const int NT = K >> 6;

  f32x4 acc[8][4] = {};
  short8 afr[4][2], bfr[2][2];

  // stage half-tile h (128 rows x 64 cols) of matrix tile into LDS buf.
  // Linear LDS dest (gl_lds requirement) + inverse-swizzled global source (rule #21).
  auto stage = [&](const unsigned short* __restrict__ G, int matBase, int buf, int h,
                   int tileR0, int k0) {
#pragma unroll
    for (int j = 0; j < 2; ++j) {
      int x = (j * 512 + tid) * 16;               // byte within 16KB half-region
      int sx = x ^ (((x >> 7) & 7) << 4);         // involution
      int grow = tileR0 + h * 128 + (x >> 7);
      int gcol = k0 + ((sx & 127) >> 1);
      unsigned short* lp = (unsigned short*)(ldsc + matBase + buf * 32768 + h * 16384 +
                                             (j * 8 + wid) * 1024);  // wave-uniform
      gl_lds16(G + (size_t)grow * K + gcol, lp);
    }
  };

  // prologue: tile0 fully + A-halves of tile1; confirm tile0 with vmcnt(4)
  stage(A, 0, 0, 0, rowA0, 0);
  stage(A, 0, 0, 1, rowA0, 0);
  stage(Bt, 65536, 0, 0, rowB0, 0);
  stage(Bt, 65536, 0, 1, rowB0, 0);
  if (NT > 1) {
    stage(A, 0, 1, 0, rowA0, 64);
    stage(A, 0, 1, 1, rowA0, 64);
    asm volatile("s_waitcnt vmcnt(4)" ::: "memory");
  } else {
    asm volatile("s_waitcnt vmcnt(0)" ::: "memory");
  }
  BARRIER();

  for (int t = 0; t < NT; ++t) {
    const int cur = t & 1;
    const int curOff = cur * 32768;
    const int nxt = cur ^ 1;
    const int k1 = (t + 1) * 64;
    const int k2 = (t + 2) * 64;
    // ---- phase 0: quadrant (0,0)
    DSA(0);
    DSB(0);
    if (t + 1 < NT) stage(Bt, 65536, nxt, 0, rowB0, k1);
    BARRIER();
    LGKM0_SCHED();
    MFMAQ(0, 0);
    BARRIER();
    // ---- phase 1: quadrant (0,1)  (reuses afr)
    DSB(2);
    if (t + 1 < NT) stage(Bt, 65536, nxt, 1, rowB0, k1);
    BARRIER();
    LGKM0_SCHED();
    MFMAQ(0, 2);
    BARRIER();
    // ---- phase 2: quadrant (1,1)  (reuses bfr)
    DSA(4);
    BARRIER();
    LGKM0_SCHED();
    MFMAQ(4, 2);
    BARRIER();
    // ---- phase 3: quadrant (1,0)  (re-reads B0; reads touch only B-regions)
    DSB(0);
    BARRIER();  // all tile-t reads of A-regions completed (per-phase lgkm0) before this
    if (t + 2 < NT) {
      // overwrite buf[cur] A-regions with tile t+2 (post-barrier: strongly race-free)
      stage(A, 0, cur, 0, rowA0, k2);
      stage(A, 0, cur, 1, rowA0, k2);
      asm volatile("s_waitcnt vmcnt(4)" ::: "memory");  // tile t+1 fully resident
    } else {
      asm volatile("s_waitcnt vmcnt(0)" ::: "memory");
    }
    LGKM0_SCHED();
    MFMAQ(4, 0);
    BARRIER();
  }

  // epilogue: C/D layout col = lane&15, row = (lane>>4)*4 + r
  const int rl = (lane >> 4) * 4;
#pragma unroll
  for (int fn = 0; fn < 4; ++fn) {
    int gc = rowB0 + wave_n * 64 + fn * 16 + frow;
    float bb = (gc < biasN) ? bias[gc] : 0.f;
    float gg = 1.f, bbe = 0.f, mm = 0.f, rs = 1.f;
    if (EPI == 1) {
      gg = g[gc];
      bbe = be[gc];
      mm = mn[gc];
      rs = rsqrtf(vr[gc] + 1e-5f);
    }
#pragma unroll
    for (int fm = 0; fm < 8; ++fm) {
      f32x4 v = acc[fm][fn];
#pragma unroll
      for (int r = 0; r < 4; ++r) {
        int gr = rowA0 + wave_m * 128 + fm * 16 + rl + r;
        float x = v[r] + bb;
        if (EPI == 1) {
          x = fmaxf(x, 0.f);
          x = gg * (x - mm) * rs + bbe;
        }
        C[(size_t)gr * N + gc] = f2bf(x);
      }
    }
  }
}

// Per-row windowed average within consecutive-equal-key segments.
__global__ __launch_bounds__(256) void pool_seg(const unsigned short* __restrict__ h,
                                                const int* __restrict__ key,
                                                unsigned short* __restrict__ pooled,
                                                int B, int D) {
  int row = blockIdx.x;
  int k0 = key[row];
  int down = 0, up = 0;
  while (down < 4 && row - down - 1 >= 0 && key[row - down - 1] == k0) ++down;
  while (up < 4 && row + up + 1 < B && key[row + up + 1] == k0) ++up;
  float inv = 1.f / (float)(down + up + 1);
  int f0 = threadIdx.x * 8;
  float s[8] = {0.f, 0.f, 0.f, 0.f, 0.f, 0.f, 0.f, 0.f};
  for (int dr = -down; dr <= up; ++dr) {
    ushort8 v = *(const ushort8*)(h + (size_t)(row + dr) * D + f0);
#pragma unroll
    for (int j = 0; j < 8; ++j) s[j] += bf2f(v[j]);
  }
  ushort8 o;
#pragma unroll
  for (int j = 0; j < 8; ++j) o[j] = f2bf(s[j] * inv);
  *(ushort8*)(pooled + (size_t)row * D + f0) = o;
}

// out rows: output_pain [B,2] then pain_pred [B,2]. 1 block per row, H = 8*blockDim.
__global__ __launch_bounds__(256) void final_head(const unsigned short* __restrict__ h2,
                                                  const float* __restrict__ Wp,
                                                  const float* __restrict__ bp,
                                                  float* __restrict__ out, int B, int H) {
  int row = blockIdx.x;
  int f0 = threadIdx.x * 8;
  ushort8 v = *(const ushort8*)(h2 + (size_t)row * H + f0);
  float4v w0a = *(const float4v*)(Wp + f0);
  float4v w0b = *(const float4v*)(Wp + f0 + 4);
  float4v w1a = *(const float4v*)(Wp + H + f0);
  float4v w1b = *(const float4v*)(Wp + H + f0 + 4);
  float a0 = 0.f, a1 = 0.f;
#pragma unroll
  for (int j = 0; j < 4; ++j) {
    float x0 = bf2f(v[j]), x1 = bf2f(v[j + 4]);
    a0 += x0 * w0a[j] + x1 * w0b[j];
    a1 += x0 * w1a[j] + x1 * w1b[j];
  }
#pragma unroll
  for (int off = 32; off > 0; off >>= 1) {
    a0 += __shfl_down(a0, off);
    a1 += __shfl_down(a1, off);
  }
  __shared__ float red[8];
  int wv = threadIdx.x >> 6;
  if ((threadIdx.x & 63) == 0) {
    red[wv] = a0;
    red[4 + wv] = a1;
  }
  __syncthreads();
  if (threadIdx.x == 0) {
    float o0 = red[0] + red[1] + red[2] + red[3] + bp[0];
    float o1 = red[4] + red[5] + red[6] + red[7] + bp[1];
    out[(size_t)row * 2] = o0;
    out[(size_t)row * 2 + 1] = o1;
    float mx = fmaxf(o0, o1);
    float e0 = expf(o0 - mx), e1 = expf(o1 - mx);
    float sden = e0 + e1;
    out[(size_t)B * 2 + (size_t)row * 2] = e0 / sden;
    out[(size_t)B * 2 + (size_t)row * 2 + 1] = e1 / sden;
  }
}

extern "C" void kernel_launch(void* const* d_in, const int* in_sizes, int n_in,
                              void* d_out, int out_size, void* d_ws, size_t ws_size,
                              hipStream_t stream) {
  (void)n_in; (void)out_size; (void)ws_size;
  const float* img = (const float*)d_in[0];
  const int* segkey = (const int*)d_in[1];
  const float* W3d = (const float*)d_in[2];
  const float* b3d = (const float*)d_in[3];
  const float* W1 = (const float*)d_in[4];
  const float* b1 = (const float*)d_in[5];
  const float* g1 = (const float*)d_in[6];
  const float* be1 = (const float*)d_in[7];
  const float* m1 = (const float*)d_in[8];
  const float* v1 = (const float*)d_in[9];
  const float* W2 = (const float*)d_in[10];
  const float* b2 = (const float*)d_in[11];
  const float* g2 = (const float*)d_in[12];
  const float* be2 = (const float*)d_in[13];
  const float* m2 = (const float*)d_in[14];
  const float* v2 = (const float*)d_in[15];
  const float* Wp = (const float*)d_in[16];
  const float* bp = (const float*)d_in[17];

  const int B = in_sizes[1];           // 16384
  const int F = in_sizes[0] / B;       // 2048
  const int D3 = in_sizes[3];          // 600
  const int H = in_sizes[5];           // 2048
  const int D3p = 768;                 // pad 600 -> 768 so all GEMMs use 256^2 tiles

  char* ws = (char*)d_ws;
  size_t off = 0;
  auto alloc = [&](size_t bytes) -> void* {
    void* p = (void*)(ws + off);
    off += (bytes + 255) & ~(size_t)255;
    return p;
  };
  unsigned short* imgb = (unsigned short*)alloc((size_t)B * F * 2);     // 67 MB
  unsigned short* W3dp = (unsigned short*)alloc((size_t)D3p * F * 2);
  unsigned short* W1p  = (unsigned short*)alloc((size_t)H * D3p * 2);
  unsigned short* W2b  = (unsigned short*)alloc((size_t)H * H * 2);
  unsigned short* lat  = (unsigned short*)alloc((size_t)B * D3p * 2);
  unsigned short* h    = (unsigned short*)alloc((size_t)B * H * 2);
  unsigned short* pooled = (unsigned short*)alloc((size_t)B * H * 2);
  unsigned short* h2 = imgb;  // img dead after G1 -> reuse for h2

  float* out = (float*)d_out;

  auto gridFor = [](size_t n4) -> int {
    size_t gsz = (n4 + 255) / 256;
    if (gsz > 4096) gsz = 4096;
    return (int)gsz;
  };

  // allow 128 KiB dynamic LDS (idempotent, host-side, graph-capture safe)
  hipFuncSetAttribute(reinterpret_cast<const void*>(gemm8p<0>),
                      hipFuncAttributeMaxDynamicSharedMemorySize, 131072);
  hipFuncSetAttribute(reinterpret_cast<const void*>(gemm8p<1>),
                      hipFuncAttributeMaxDynamicSharedMemorySize, 131072);

  // casts (with zero-padding where needed)
  cast_pad<<<gridFor((size_t)B * F / 4), 256, 0, stream>>>(img, imgb, B, F, B, F);
  cast_pad<<<gridFor((size_t)D3p * F / 4), 256, 0, stream>>>(W3d, W3dp, D3, F, D3p, F);
  cast_pad<<<gridFor((size_t)H * D3p / 4), 256, 0, stream>>>(W1, W1p, H, D3, H, D3p);
  cast_pad<<<gridFor((size_t)H * H / 4), 256, 0, stream>>>(W2, W2b, H, H, H, H);

  dim3 blk(512);
  // G1: latent[B x D3p] = img @ W3d^T + b3d (pad cols produce exact 0)
  gemm8p<0><<<dim3(B / 256, D3p / 256), blk, 131072, stream>>>(
      imgb, W3dp, lat, B, D3p, F, b3d, D3, nullptr, nullptr, nullptr, nullptr);
  // G2: h = BN(ReLU(latent @ W1^T + b1)), K = D3p (zero-padded, exact)
  gemm8p<1><<<dim3(B / 256, H / 256), blk, 131072, stream>>>(
      lat, W1p, h, B, H, D3p, b1, H, g1, be1, m1, v1);
  // segment windowed avg pool
  pool_seg<<<B, H / 8, 0, stream>>>(h, segkey, pooled, B, H);
  // G3: h2 = BN(ReLU(pooled @ W2^T + b2))
  gemm8p<1><<<dim3(B / 256, H / 256), blk, 131072, stream>>>(
      pooled, W2b, h2, B, H, H, b2, H, g2, be2, m2, v2);
  // final linear + softmax
  final_head<<<B, H / 8, 0, stream>>>(h2, Wp, bp, out, B, H);
}

// Round 3
// 627.309 us; speedup vs baseline: 1.1566x; 1.0239x over previous
//
#include <hip/hip_runtime.h>
#include <hip/hip_bf16.h>
#include <math.h>
#include <stdint.h>

#define DEVI static __device__ __forceinline__

typedef __attribute__((ext_vector_type(8))) short short8;       // MFMA A/B frag (8 bf16)
typedef __attribute__((ext_vector_type(4))) float f32x4;        // MFMA C/D frag
typedef __attribute__((ext_vector_type(4))) float float4v;
typedef __attribute__((ext_vector_type(4))) unsigned short ushort4v;
typedef __attribute__((ext_vector_type(8))) unsigned short ushort8;

// fp32 -> bf16 bits, round-to-nearest-even (finite inputs only)
DEVI unsigned short f2bf(float f) {
  unsigned int u = __builtin_bit_cast(unsigned int, f);
  u += 0x7fffu + ((u >> 16) & 1u);
  return (unsigned short)(u >> 16);
}
DEVI float bf2f(unsigned short s) {
  unsigned int u = ((unsigned int)s) << 16;
  return __builtin_bit_cast(float, u);
}

// async global->LDS, 16B per lane. lds ptr must be wave-uniform base; HW adds lane*16.
DEVI void gl_lds16(const unsigned short* g, unsigned short* l) {
  __builtin_amdgcn_global_load_lds(
      (const __attribute__((address_space(1))) void*)g,
      (__attribute__((address_space(3))) void*)l, 16, 0, 0);
}

// dst[r][c] = (r<srcR && c<srcC) ? bf16(src[r][c]) : 0   (dstC % 4 == 0)
__global__ __launch_bounds__(256) void cast_pad(const float* __restrict__ src,
                                                unsigned short* __restrict__ dst,
                                                int srcR, int srcC, int dstR, int dstC) {
  size_t n4 = (size_t)dstR * (size_t)dstC / 4;
  for (size_t i = (size_t)blockIdx.x * blockDim.x + threadIdx.x; i < n4;
       i += (size_t)gridDim.x * blockDim.x) {
    size_t e = i * 4;
    int r = (int)(e / (size_t)dstC);
    int c = (int)(e % (size_t)dstC);
    float4v v;
    if (r < srcR && c + 3 < srcC) {
      v = *(const float4v*)(src + (size_t)r * srcC + c);
    } else {
#pragma unroll
      for (int j = 0; j < 4; ++j) {
        int cc = c + j;
        v[j] = (r < srcR && cc < srcC) ? src[(size_t)r * srcC + cc] : 0.f;
      }
    }
    ushort4v o;
#pragma unroll
    for (int j = 0; j < 4; ++j) o[j] = f2bf(v[j]);
    *(ushort4v*)(dst + e) = o;
  }
}

#define BARRIER()                                   \
  do {                                              \
    asm volatile("" ::: "memory");                  \
    __builtin_amdgcn_s_barrier();                   \
    asm volatile("" ::: "memory");                  \
  } while (0)
#define LGKM0_SCHED()                                        \
  do {                                                       \
    asm volatile("s_waitcnt lgkmcnt(0)" ::: "memory");       \
    __builtin_amdgcn_sched_barrier(0);                       \
  } while (0)
#define VMCNT(N) asm volatile("s_waitcnt vmcnt(" #N ")" ::: "memory")

// ds_read of A quadrant from buffer CUR (CUR literal 0/1); addresses = reg + imm.
#define DSA2(CUR, fmBase)                                                     \
  _Pragma("unroll") for (int i_ = 0; i_ < 4; ++i_)                            \
  _Pragma("unroll") for (int kk_ = 0; kk_ < 2; ++kk_)                         \
      afr[i_][kk_] = *(const short8*)(ldsc + (CUR) * 32768 + aBase[kk_] +     \
                                      ((fmBase) + i_) * 2048);

#define DSB2(CUR, fnBase)                                                     \
  _Pragma("unroll") for (int j_ = 0; j_ < 2; ++j_)                            \
  _Pragma("unroll") for (int kk_ = 0; kk_ < 2; ++kk_)                         \
      bfr[j_][kk_] = *(const short8*)(ldsc + 65536 + (CUR) * 32768 +          \
                                      bBase[kk_] + ((fnBase) + j_) * 2048);

// one C-quadrant: 16 MFMA wrapped in setprio (T5)
#define MFMAQ(fmB, fnB)                                                       \
  __builtin_amdgcn_s_setprio(1);                                              \
  _Pragma("unroll") for (int i_ = 0; i_ < 4; ++i_)                            \
  _Pragma("unroll") for (int j_ = 0; j_ < 2; ++j_)                            \
  _Pragma("unroll") for (int kk_ = 0; kk_ < 2; ++kk_)                         \
      acc[(fmB) + i_][(fnB) + j_] = __builtin_amdgcn_mfma_f32_16x16x32_bf16(  \
          afr[i_][kk_], bfr[j_][kk_], acc[(fmB) + i_][(fnB) + j_], 0, 0, 0);  \
  __builtin_amdgcn_s_setprio(0);                                              \
  __builtin_amdgcn_sched_barrier(0);

// stage half h (128 rows x 64 cols) of K-tile tt into LDS buf BUF (static indices).
// Linear LDS dest (gl_lds requirement) + inverse-swizzled per-lane global source.
#define STAGE_A(BUF, h, tt)                                                   \
  _Pragma("unroll") for (int j_ = 0; j_ < 2; ++j_)                            \
      gl_lds16(pA + (size_t)((h) * 128 + j_ * 64) * Ks + (size_t)(tt) * 64,   \
               (unsigned short*)(ldsc + (BUF) * 32768 + (h) * 16384 +         \
                                 (j_ * 8 + wid) * 1024));
#define STAGE_B(BUF, h, tt)                                                   \
  _Pragma("unroll") for (int j_ = 0; j_ < 2; ++j_)                            \
      gl_lds16(pB + (size_t)((h) * 128 + j_ * 64) * Ks + (size_t)(tt) * 64,   \
               (unsigned short*)(ldsc + 65536 + (BUF) * 32768 + (h) * 16384 + \
                                 (j_ * 8 + wid) * 1024));

// C = A @ Bt^T (+ epilogue). 256x256 tile, BK=64, 512 threads = 8 waves (2M x 4N).
// m201 structure: 8 phases / 2 K-tiles per iteration (static buffer parity),
// T2 LDS XOR-swizzle, T4 counted vmcnt(4), T5 setprio. Requires NT = K/64 even.
// EPI 0: +bias -> bf16.  EPI 1: +bias, ReLU, BN -> bf16.
template <int EPI>
__global__ __launch_bounds__(512, 1) void gemm8p(
    const unsigned short* __restrict__ A, const unsigned short* __restrict__ Bt,
    unsigned short* __restrict__ C, int M, int N, int K,
    const float* __restrict__ bias, int biasN,
    const float* __restrict__ g, const float* __restrict__ be,
    const float* __restrict__ mn, const float* __restrict__ vr) {
  extern __shared__ unsigned short lds[];
  char* ldsc = (char*)lds;
  const int tid = threadIdx.x;
  const int wid = tid >> 6;
  const int lane = tid & 63;
  const int wave_m = wid >> 2;   // 0..1
  const int wave_n = wid & 3;    // 0..3
  const int rowA0 = blockIdx.x * 256;
  const int rowB0 = blockIdx.y * 256;
  const int frow = lane & 15;
  const int fk16 = (lane >> 4) * 16;        // byte offset of k-subfrag within 64B row span
  const int xorv = (frow & 7) << 4;         // T2 swizzle term
  const int NT = K >> 6;
  const size_t Ks = (size_t)K;

  // per-lane LDS read bases: addr = ldsc + CUR*32768 + base[kk] + fm*2048 (+65536 for B)
  // exact because xorv only touches bits 4-6, disjoint from row/fm contributions.
  const int arow0 = (wave_m * 128 + frow) * 128;
  const int brow0 = (wave_n * 64 + frow) * 128;
  const int aBase[2] = {arow0 + ((0 + fk16) ^ xorv), arow0 + ((64 + fk16) ^ xorv)};
  const int bBase[2] = {brow0 + ((0 + fk16) ^ xorv), brow0 + ((64 + fk16) ^ xorv)};

  // per-lane global staging bases (swizzle-compensated source)
  const int srow = tid >> 3;                                        // 0..63
  const int scolb = (((tid & 7) * 16) ^ (((tid >> 3) & 7) << 4));   // byte within 128B row
  const unsigned short* pA = A + (size_t)(rowA0 + srow) * Ks + (scolb >> 1);
  const unsigned short* pB = Bt + (size_t)(rowB0 + srow) * Ks + (scolb >> 1);

  f32x4 acc[8][4] = {};
  short8 afr[4][2], bfr[2][2];

  // prologue: tile0 fully + tile1 A-halves; vmcnt(4) -> tile0 resident
  STAGE_A(0, 0, 0);
  STAGE_A(0, 1, 0);
  STAGE_B(0, 0, 0);
  STAGE_B(0, 1, 0);
  if (NT > 1) {
    STAGE_A(1, 0, 1);
    STAGE_A(1, 1, 1);
    VMCNT(4);
  } else {
    VMCNT(0);
  }
  BARRIER();

  for (int t = 0; t < NT; t += 2) {
    // ================= tile t (buf 0) =================
    DSA2(0, 0);
    DSB2(0, 0);
    STAGE_B(1, 0, t + 1);
    BARRIER();
    LGKM0_SCHED();
    MFMAQ(0, 0);
    BARRIER();

    DSB2(0, 2);
    STAGE_B(1, 1, t + 1);
    BARRIER();
    LGKM0_SCHED();
    MFMAQ(0, 2);
    BARRIER();

    DSA2(0, 4);
    BARRIER();
    LGKM0_SCHED();
    MFMAQ(4, 2);
    BARRIER();

    DSB2(0, 0);
    BARRIER();  // all reads of buf0 A-region complete before overwrite below
    if (t + 2 < NT) {
      STAGE_A(0, 0, t + 2);
      STAGE_A(0, 1, t + 2);
      VMCNT(4);  // completes A(t+1) + B(t+1) -> tile t+1 resident
    } else {
      VMCNT(0);
    }
    LGKM0_SCHED();
    MFMAQ(4, 0);
    BARRIER();

    // ================= tile t+1 (buf 1) =================
    DSA2(1, 0);
    DSB2(1, 0);
    if (t + 2 < NT) STAGE_B(0, 0, t + 2);
    BARRIER();
    LGKM0_SCHED();
    MFMAQ(0, 0);
    BARRIER();

    DSB2(1, 2);
    if (t + 2 < NT) STAGE_B(0, 1, t + 2);
    BARRIER();
    LGKM0_SCHED();
    MFMAQ(0, 2);
    BARRIER();

    DSA2(1, 4);
    BARRIER();
    LGKM0_SCHED();
    MFMAQ(4, 2);
    BARRIER();

    DSB2(1, 0);
    BARRIER();
    if (t + 3 < NT) {
      STAGE_A(1, 0, t + 3);
      STAGE_A(1, 1, t + 3);
      VMCNT(4);  // completes A(t+2) + B(t+2) -> tile t+2 resident
    } else {
      VMCNT(0);
    }
    LGKM0_SCHED();
    MFMAQ(4, 0);
    BARRIER();
  }

  // epilogue: C/D layout col = lane&15, row = (lane>>4)*4 + r
  const int rl = (lane >> 4) * 4;
#pragma unroll
  for (int fn = 0; fn < 4; ++fn) {
    int gc = rowB0 + wave_n * 64 + fn * 16 + frow;
    float bb = (gc < biasN) ? bias[gc] : 0.f;
    float gg = 1.f, bbe = 0.f, mm = 0.f, rs = 1.f;
    if (EPI == 1) {
      gg = g[gc];
      bbe = be[gc];
      mm = mn[gc];
      rs = rsqrtf(vr[gc] + 1e-5f);
    }
#pragma unroll
    for (int fm = 0; fm < 8; ++fm) {
      f32x4 v = acc[fm][fn];
#pragma unroll
      for (int r = 0; r < 4; ++r) {
        int gr = rowA0 + wave_m * 128 + fm * 16 + rl + r;
        float x = v[r] + bb;
        if (EPI == 1) {
          x = fmaxf(x, 0.f);
          x = gg * (x - mm) * rs + bbe;
        }
        C[(size_t)gr * N + gc] = f2bf(x);
      }
    }
  }
}

// Per-row windowed average within consecutive-equal-key segments.
__global__ __launch_bounds__(256) void pool_seg(const unsigned short* __restrict__ h,
                                                const int* __restrict__ key,
                                                unsigned short* __restrict__ pooled,
                                                int B, int D) {
  int row = blockIdx.x;
  int k0 = key[row];
  int down = 0, up = 0;
  while (down < 4 && row - down - 1 >= 0 && key[row - down - 1] == k0) ++down;
  while (up < 4 && row + up + 1 < B && key[row + up + 1] == k0) ++up;
  float inv = 1.f / (float)(down + up + 1);
  int f0 = threadIdx.x * 8;
  float s[8] = {0.f, 0.f, 0.f, 0.f, 0.f, 0.f, 0.f, 0.f};
  for (int dr = -down; dr <= up; ++dr) {
    ushort8 v = *(const ushort8*)(h + (size_t)(row + dr) * D + f0);
#pragma unroll
    for (int j = 0; j < 8; ++j) s[j] += bf2f(v[j]);
  }
  ushort8 o;
#pragma unroll
  for (int j = 0; j < 8; ++j) o[j] = f2bf(s[j] * inv);
  *(ushort8*)(pooled + (size_t)row * D + f0) = o;
}

// out rows: output_pain [B,2] then pain_pred [B,2]. 1 block per row, H = 8*blockDim.
__global__ __launch_bounds__(256) void final_head(const unsigned short* __restrict__ h2,
                                                  const float* __restrict__ Wp,
                                                  const float* __restrict__ bp,
                                                  float* __restrict__ out, int B, int H) {
  int row = blockIdx.x;
  int f0 = threadIdx.x * 8;
  ushort8 v = *(const ushort8*)(h2 + (size_t)row * H + f0);
  float4v w0a = *(const float4v*)(Wp + f0);
  float4v w0b = *(const float4v*)(Wp + f0 + 4);
  float4v w1a = *(const float4v*)(Wp + H + f0);
  float4v w1b = *(const float4v*)(Wp + H + f0 + 4);
  float a0 = 0.f, a1 = 0.f;
#pragma unroll
  for (int j = 0; j < 4; ++j) {
    float x0 = bf2f(v[j]), x1 = bf2f(v[j + 4]);
    a0 += x0 * w0a[j] + x1 * w0b[j];
    a1 += x0 * w1a[j] + x1 * w1b[j];
  }
#pragma unroll
  for (int off = 32; off > 0; off >>= 1) {
    a0 += __shfl_down(a0, off);
    a1 += __shfl_down(a1, off);
  }
  __shared__ float red[8];
  int wv = threadIdx.x >> 6;
  if ((threadIdx.x & 63) == 0) {
    red[wv] = a0;
    red[4 + wv] = a1;
  }
  __syncthreads();
  if (threadIdx.x == 0) {
    float o0 = red[0] + red[1] + red[2] + red[3] + bp[0];
    float o1 = red[4] + red[5] + red[6] + red[7] + bp[1];
    out[(size_t)row * 2] = o0;
    out[(size_t)row * 2 + 1] = o1;
    float mx = fmaxf(o0, o1);
    float e0 = expf(o0 - mx), e1 = expf(o1 - mx);
    float sden = e0 + e1;
    out[(size_t)B * 2 + (size_t)row * 2] = e0 / sden;
    out[(size_t)B * 2 + (size_t)row * 2 + 1] = e1 / sden;
  }
}

extern "C" void kernel_launch(void* const* d_in, const int* in_sizes, int n_in,
                              void* d_out, int out_size, void* d_ws, size_t ws_size,
                              hipStream_t stream) {
  (void)n_in; (void)out_size; (void)ws_size;
  const float* img = (const float*)d_in[0];
  const int* segkey = (const int*)d_in[1];
  const float* W3d = (const float*)d_in[2];
  const float* b3d = (const float*)d_in[3];
  const float* W1 = (const float*)d_in[4];
  const float* b1 = (const float*)d_in[5];
  const float* g1 = (const float*)d_in[6];
  const float* be1 = (const float*)d_in[7];
  const float* m1 = (const float*)d_in[8];
  const float* v1 = (const float*)d_in[9];
  const float* W2 = (const float*)d_in[10];
  const float* b2 = (const float*)d_in[11];
  const float* g2 = (const float*)d_in[12];
  const float* be2 = (const float*)d_in[13];
  const float* m2 = (const float*)d_in[14];
  const float* v2 = (const float*)d_in[15];
  const float* Wp = (const float*)d_in[16];
  const float* bp = (const float*)d_in[17];

  const int B = in_sizes[1];           // 16384
  const int F = in_sizes[0] / B;       // 2048
  const int D3 = in_sizes[3];          // 600
  const int H = in_sizes[5];           // 2048
  const int D3p = 768;                 // pad 600 -> 768 so all GEMMs use 256^2 tiles

  char* ws = (char*)d_ws;
  size_t off = 0;
  auto alloc = [&](size_t bytes) -> void* {
    void* p = (void*)(ws + off);
    off += (bytes + 255) & ~(size_t)255;
    return p;
  };
  unsigned short* imgb = (unsigned short*)alloc((size_t)B * F * 2);     // 67 MB
  unsigned short* W3dp = (unsigned short*)alloc((size_t)D3p * F * 2);
  unsigned short* W1p  = (unsigned short*)alloc((size_t)H * D3p * 2);
  unsigned short* W2b  = (unsigned short*)alloc((size_t)H * H * 2);
  unsigned short* lat  = (unsigned short*)alloc((size_t)B * D3p * 2);
  unsigned short* h    = (unsigned short*)alloc((size_t)B * H * 2);
  unsigned short* pooled = (unsigned short*)alloc((size_t)B * H * 2);
  unsigned short* h2 = imgb;  // img dead after G1 -> reuse for h2

  float* out = (float*)d_out;

  auto gridFor = [](size_t n4) -> int {
    size_t gsz = (n4 + 255) / 256;
    if (gsz > 4096) gsz = 4096;
    return (int)gsz;
  };

  // allow 128 KiB dynamic LDS (idempotent, host-side, graph-capture safe)
  hipFuncSetAttribute(reinterpret_cast<const void*>(gemm8p<0>),
                      hipFuncAttributeMaxDynamicSharedMemorySize, 131072);
  hipFuncSetAttribute(reinterpret_cast<const void*>(gemm8p<1>),
                      hipFuncAttributeMaxDynamicSharedMemorySize, 131072);

  // casts (with zero-padding where needed)
  cast_pad<<<gridFor((size_t)B * F / 4), 256, 0, stream>>>(img, imgb, B, F, B, F);
  cast_pad<<<gridFor((size_t)D3p * F / 4), 256, 0, stream>>>(W3d, W3dp, D3, F, D3p, F);
  cast_pad<<<gridFor((size_t)H * D3p / 4), 256, 0, stream>>>(W1, W1p, H, D3, H, D3p);
  cast_pad<<<gridFor((size_t)H * H / 4), 256, 0, stream>>>(W2, W2b, H, H, H, H);

  dim3 blk(512);
  // G1: latent[B x D3p] = img @ W3d^T + b3d (pad cols produce exact 0)
  gemm8p<0><<<dim3(B / 256, D3p / 256), blk, 131072, stream>>>(
      imgb, W3dp, lat, B, D3p, F, b3d, D3, nullptr, nullptr, nullptr, nullptr);
  // G2: h = BN(ReLU(latent @ W1^T + b1)), K = D3p (zero-padded, exact)
  gemm8p<1><<<dim3(B / 256, H / 256), blk, 131072, stream>>>(
      lat, W1p, h, B, H, D3p, b1, H, g1, be1, m1, v1);
  // segment windowed avg pool
  pool_seg<<<B, H / 8, 0, stream>>>(h, segkey, pooled, B, H);
  // G3: h2 = BN(ReLU(pooled @ W2^T + b2))
  gemm8p<1><<<dim3(B / 256, H / 256), blk, 131072, stream>>>(
      pooled, W2b, h2, B, H, H, b2, H, g2, be2, m2, v2);
  // final linear + softmax
  final_head<<<B, H / 8, 0, stream>>>(h2, Wp, bp, out, B, H);
}